// Round 1
// baseline (1014.798 us; speedup 1.0000x reference)
//
#include <hip/hip_runtime.h>
#include <hip/hip_fp16.h>

typedef _Float16 half_t;
typedef __attribute__((ext_vector_type(8))) _Float16 half8;
typedef __attribute__((ext_vector_type(4))) _Float16 half4;
typedef __attribute__((ext_vector_type(4))) float f32x4;

#define D_MODEL 1024
#define NHEAD 16
#define HDIM 64
#define BATCH 4
#define SEQ 2048
#define M_TOTAL (BATCH*SEQ)   // 8192

// ---------------------------------------------------------------------------
// GEMM: C = A @ B^T + bias.  A [8192 x 1024], B [1024 x 1024] row-major (NT).
// OUTMODE 0: fp16 out, head layout [B,H,S,64]
// OUTMODE 1: fp16 out, transposed head layout [B,H,64,S]   (for V)
// OUTMODE 2: fp32 out, plain [M,N]                          (final proj)
// A_HALF: A is fp16 (ctx) instead of fp32.
// ---------------------------------------------------------------------------
#define BM 128
#define BN 128
#define BKK 32
#define LDT 40   // padded LDS stride in halves (breaks bank conflicts)

template<int OUTMODE, bool A_HALF>
__global__ __launch_bounds__(256)
void gemm_bt(const void* __restrict__ Ap, const float* __restrict__ Bp,
             const float* __restrict__ bias, void* __restrict__ outp)
{
    __shared__ half_t As[BM * LDT];
    __shared__ half_t Bs[BN * LDT];

    const int tid  = threadIdx.x;
    const int lane = tid & 63;
    const int w    = tid >> 6;
    const int wm   = w >> 1, wn = w & 1;
    const int g    = lane >> 4, c = lane & 15;
    const int bm   = blockIdx.y * BM;
    const int bn   = blockIdx.x * BN;
    const int K    = 1024;

    f32x4 acc[4][4] = {};

    float4 fa[4];
    float4 fb[4];
    uint4  ha[2];

    auto load_tile = [&](int kt) {
        const int kb = kt * BKK;
        if (A_HALF) {
            const half_t* A = (const half_t*)Ap;
#pragma unroll
            for (int i = 0; i < 2; ++i) {
                const int row = (tid >> 2) + i * 64;
                const int col = (tid & 3) * 8;
                ha[i] = *(const uint4*)&A[(size_t)(bm + row) * K + kb + col];
            }
        } else {
            const float* A = (const float*)Ap;
#pragma unroll
            for (int i = 0; i < 4; ++i) {
                const int row = (tid >> 3) + i * 32;
                const int col = (tid & 7) * 4;
                fa[i] = *(const float4*)&A[(size_t)(bm + row) * K + kb + col];
            }
        }
#pragma unroll
        for (int i = 0; i < 4; ++i) {
            const int row = (tid >> 3) + i * 32;
            const int col = (tid & 7) * 4;
            fb[i] = *(const float4*)&Bp[(size_t)(bn + row) * K + kb + col];
        }
    };

    auto store_tile = [&]() {
        if (A_HALF) {
#pragma unroll
            for (int i = 0; i < 2; ++i) {
                const int row = (tid >> 2) + i * 64;
                const int col = (tid & 3) * 8;
                *(uint4*)&As[row * LDT + col] = ha[i];
            }
        } else {
#pragma unroll
            for (int i = 0; i < 4; ++i) {
                const int row = (tid >> 3) + i * 32;
                const int col = (tid & 7) * 4;
                half4 h = { (half_t)fa[i].x, (half_t)fa[i].y, (half_t)fa[i].z, (half_t)fa[i].w };
                *(half4*)&As[row * LDT + col] = h;
            }
        }
#pragma unroll
        for (int i = 0; i < 4; ++i) {
            const int row = (tid >> 3) + i * 32;
            const int col = (tid & 7) * 4;
            half4 h = { (half_t)fb[i].x, (half_t)fb[i].y, (half_t)fb[i].z, (half_t)fb[i].w };
            *(half4*)&Bs[row * LDT + col] = h;
        }
    };

    load_tile(0);
    const int NT = K / BKK;  // 32
    for (int kt = 0; kt < NT; ++kt) {
        __syncthreads();
        store_tile();
        __syncthreads();
        if (kt + 1 < NT) load_tile(kt + 1);

        half8 af[4], bf[4];
#pragma unroll
        for (int mt = 0; mt < 4; ++mt)
            af[mt] = *(const half8*)&As[(wm * 64 + mt * 16 + c) * LDT + g * 8];
#pragma unroll
        for (int nt = 0; nt < 4; ++nt)
            bf[nt] = *(const half8*)&Bs[(wn * 64 + nt * 16 + c) * LDT + g * 8];
#pragma unroll
        for (int mt = 0; mt < 4; ++mt)
#pragma unroll
            for (int nt = 0; nt < 4; ++nt)
                acc[mt][nt] = __builtin_amdgcn_mfma_f32_16x16x32_f16(af[mt], bf[nt], acc[mt][nt], 0, 0, 0);
    }

#pragma unroll
    for (int mt = 0; mt < 4; ++mt)
#pragma unroll
        for (int nt = 0; nt < 4; ++nt)
#pragma unroll
            for (int j = 0; j < 4; ++j) {
                const int gm = bm + wm * 64 + mt * 16 + g * 4 + j;
                const int gn = bn + wn * 64 + nt * 16 + c;
                const float val = acc[mt][nt][j] + bias[gn];
                if (OUTMODE == 0) {
                    const int b = gm >> 11, s = gm & 2047, h = gn >> 6, d = gn & 63;
                    ((half_t*)outp)[((size_t)(b * NHEAD + h) * SEQ + s) * HDIM + d] = (half_t)val;
                } else if (OUTMODE == 1) {
                    const int b = gm >> 11, s = gm & 2047, h = gn >> 6, d = gn & 63;
                    ((half_t*)outp)[((size_t)(b * NHEAD + h) * HDIM + d) * SEQ + s] = (half_t)val;
                } else {
                    ((float*)outp)[(size_t)gm * 1024 + gn] = val;
                }
            }
}

// ---------------------------------------------------------------------------
// Fused attention per (b,h, 16-row q-block):
//   scores in registers -> softmax stats (shfl + LDS) -> normalized attn
//   written to d_out -> PV re-reads attn (L2-hot) as A-fragments.
// ---------------------------------------------------------------------------
__global__ __launch_bounds__(256)
void attn_fused(const half_t* __restrict__ qh, const half_t* __restrict__ kh,
                const half_t* __restrict__ vT, float* __restrict__ attn,
                half_t* __restrict__ ctx)
{
    __shared__ float redmax[4][16];
    __shared__ float redsum[4][16];
    __shared__ float ctxred[4][16][64];

    const int bid  = blockIdx.x;
    const int bh   = bid >> 7;     // 0..63
    const int qb   = bid & 127;
    const int tid  = threadIdx.x;
    const int w    = tid >> 6;
    const int lane = tid & 63;
    const int g    = lane >> 4, c = lane & 15;
    const int qbase = qb * 16;
    const size_t hoff = (size_t)bh * SEQ * HDIM;

    // Q fragments (A operand): row = c, k = g*8 (+32 for second half of hd)
    const half8 a0 = *(const half8*)&qh[hoff + (size_t)(qbase + c) * HDIM + g * 8];
    const half8 a1 = *(const half8*)&qh[hoff + (size_t)(qbase + c) * HDIM + g * 8 + 32];

    const int cb = w * 512;  // this wave's k-column range
    f32x4 s[32];
#pragma unroll
    for (int t = 0; t < 32; ++t) {
        const int kc = cb + t * 16;
        const half8 b0 = *(const half8*)&kh[hoff + (size_t)(kc + c) * HDIM + g * 8];
        const half8 b1 = *(const half8*)&kh[hoff + (size_t)(kc + c) * HDIM + g * 8 + 32];
        f32x4 a = {0.f, 0.f, 0.f, 0.f};
        a = __builtin_amdgcn_mfma_f32_16x16x32_f16(a0, b0, a, 0, 0, 0);
        a = __builtin_amdgcn_mfma_f32_16x16x32_f16(a1, b1, a, 0, 0, 0);
        s[t] = a * 0.125f;   // 1/sqrt(64)
    }

    // --- row max (rows g*4+j live in lanes g*16..g*16+15, cols = c x tiles)
    float mrow[4] = {-1e30f, -1e30f, -1e30f, -1e30f};
#pragma unroll
    for (int t = 0; t < 32; ++t)
#pragma unroll
        for (int j = 0; j < 4; ++j) mrow[j] = fmaxf(mrow[j], s[t][j]);
#pragma unroll
    for (int j = 0; j < 4; ++j) {
        mrow[j] = fmaxf(mrow[j], __shfl_xor(mrow[j], 1));
        mrow[j] = fmaxf(mrow[j], __shfl_xor(mrow[j], 2));
        mrow[j] = fmaxf(mrow[j], __shfl_xor(mrow[j], 4));
        mrow[j] = fmaxf(mrow[j], __shfl_xor(mrow[j], 8));
    }
    if (c == 0) {
#pragma unroll
        for (int j = 0; j < 4; ++j) redmax[w][g * 4 + j] = mrow[j];
    }
    __syncthreads();
    float M[4];
#pragma unroll
    for (int j = 0; j < 4; ++j) {
        const int r = g * 4 + j;
        M[j] = fmaxf(fmaxf(redmax[0][r], redmax[1][r]), fmaxf(redmax[2][r], redmax[3][r]));
    }

    // --- exp + row sum
    float sum[4] = {0.f, 0.f, 0.f, 0.f};
#pragma unroll
    for (int t = 0; t < 32; ++t)
#pragma unroll
        for (int j = 0; j < 4; ++j) {
            const float p = __expf(s[t][j] - M[j]);
            s[t][j] = p;
            sum[j] += p;
        }
#pragma unroll
    for (int j = 0; j < 4; ++j) {
        sum[j] += __shfl_xor(sum[j], 1);
        sum[j] += __shfl_xor(sum[j], 2);
        sum[j] += __shfl_xor(sum[j], 4);
        sum[j] += __shfl_xor(sum[j], 8);
    }
    if (c == 0) {
#pragma unroll
        for (int j = 0; j < 4; ++j) redsum[w][g * 4 + j] = sum[j];
    }
    __syncthreads();
    float inv[4];
#pragma unroll
    for (int j = 0; j < 4; ++j) {
        const int r = g * 4 + j;
        inv[j] = 1.0f / (redsum[0][r] + redsum[1][r] + redsum[2][r] + redsum[3][r]);
    }

    // --- write normalized attn to d_out
    float* arow = attn + (size_t)(bh * SEQ + qbase) * SEQ;
#pragma unroll
    for (int t = 0; t < 32; ++t)
#pragma unroll
        for (int j = 0; j < 4; ++j)
            arow[(size_t)(g * 4 + j) * SEQ + cb + t * 16 + c] = s[t][j] * inv[j];
    __syncthreads();   // attn visible block-wide via L2

    // --- PV: each wave covers its own K-slice for all 4 hd tiles
    f32x4 cacc[4] = {};
#pragma unroll
    for (int kt = 0; kt < 16; ++kt) {
        const int k0 = w * 512 + kt * 32 + g * 8;
        const float4 p0 = *(const float4*)&arow[(size_t)c * SEQ + k0];
        const float4 p1 = *(const float4*)&arow[(size_t)c * SEQ + k0 + 4];
        const half8 pa = { (half_t)p0.x, (half_t)p0.y, (half_t)p0.z, (half_t)p0.w,
                           (half_t)p1.x, (half_t)p1.y, (half_t)p1.z, (half_t)p1.w };
#pragma unroll
        for (int nt = 0; nt < 4; ++nt) {
            const half8 vb = *(const half8*)&vT[(size_t)bh * HDIM * SEQ + (size_t)(nt * 16 + c) * SEQ + k0];
            cacc[nt] = __builtin_amdgcn_mfma_f32_16x16x32_f16(pa, vb, cacc[nt], 0, 0, 0);
        }
    }
#pragma unroll
    for (int nt = 0; nt < 4; ++nt)
#pragma unroll
        for (int j = 0; j < 4; ++j)
            ctxred[w][g * 4 + j][nt * 16 + c] = cacc[nt][j];
    __syncthreads();

    const int b = bh >> 4, h = bh & 15;
#pragma unroll
    for (int i = 0; i < 4; ++i) {
        const int p   = tid + 256 * i;
        const int row = p >> 6, col = p & 63;
        const float v = ctxred[0][row][col] + ctxred[1][row][col] +
                        ctxred[2][row][col] + ctxred[3][row][col];
        ctx[(size_t)(b * SEQ + qbase + row) * D_MODEL + h * HDIM + col] = (half_t)v;
    }
}

// ---------------------------------------------------------------------------
extern "C" void kernel_launch(void* const* d_in, const int* in_sizes, int n_in,
                              void* d_out, int out_size, void* d_ws, size_t ws_size,
                              hipStream_t stream) {
    const float* Qin = (const float*)d_in[0];
    const float* Kin = (const float*)d_in[1];
    const float* Vin = (const float*)d_in[2];
    const float* WQw = (const float*)d_in[3];
    const float* WQb = (const float*)d_in[4];
    const float* WKw = (const float*)d_in[5];
    const float* WKb = (const float*)d_in[6];
    const float* WVw = (const float*)d_in[7];
    const float* WVb = (const float*)d_in[8];
    const float* WOw = (const float*)d_in[9];
    const float* WOb = (const float*)d_in[10];

    char* ws = (char*)d_ws;
    half_t* qh  = (half_t*)(ws);
    half_t* kh  = (half_t*)(ws + (size_t)16 * 1024 * 1024);
    half_t* vT  = (half_t*)(ws + (size_t)32 * 1024 * 1024);
    half_t* ctx = (half_t*)(ws + (size_t)48 * 1024 * 1024);

    float* out  = (float*)d_out;
    float* attn = out + (size_t)M_TOTAL * D_MODEL;   // 8,388,608

    dim3 grid(8, 64), blk(256);
    hipLaunchKernelGGL((gemm_bt<0, false>), grid, blk, 0, stream, Qin, WQw, WQb, qh);
    hipLaunchKernelGGL((gemm_bt<0, false>), grid, blk, 0, stream, Kin, WKw, WKb, kh);
    hipLaunchKernelGGL((gemm_bt<1, false>), grid, blk, 0, stream, Vin, WVw, WVb, vT);
    hipLaunchKernelGGL(attn_fused, dim3(64 * 128), blk, 0, stream, qh, kh, vT, attn, ctx);
    hipLaunchKernelGGL((gemm_bt<2, true>), grid, blk, 0, stream, ctx, WOw, WOb, out);
}

// Round 2
// 715.250 us; speedup vs baseline: 1.4188x; 1.4188x over previous
//
#include <hip/hip_runtime.h>
#include <hip/hip_fp16.h>

typedef _Float16 half_t;
typedef __attribute__((ext_vector_type(8))) _Float16 half8;
typedef __attribute__((ext_vector_type(4))) _Float16 half4;
typedef __attribute__((ext_vector_type(4))) float f32x4;

#define D_MODEL 1024
#define NHEAD 16
#define HDIM 64
#define BATCH 4
#define SEQ 2048
#define M_TOTAL (BATCH*SEQ)   // 8192

// ---------------------------------------------------------------------------
// GEMM: C = A @ B^T + bias.  A [8192 x 1024], B [1024 x 1024] row-major (NT).
// OUTMODE 0: fp16 out, head layout [B,H,S,64]
// OUTMODE 1: fp16 out, transposed head layout [B,H,64,S]   (for V)
// OUTMODE 2: fp32 out, plain [M,N]                          (final proj)
// A_HALF: A is fp16 (ctx) instead of fp32.
// ---------------------------------------------------------------------------
#define BM 128
#define BN 128
#define BKK 32
#define LDT 40   // padded LDS stride in halves (breaks bank conflicts)

template<int OUTMODE, bool A_HALF>
__global__ __launch_bounds__(256)
void gemm_bt(const void* __restrict__ Ap, const float* __restrict__ Bp,
             const float* __restrict__ bias, void* __restrict__ outp)
{
    __shared__ half_t As[BM * LDT];
    __shared__ half_t Bs[BN * LDT];

    const int tid  = threadIdx.x;
    const int lane = tid & 63;
    const int w    = tid >> 6;
    const int wm   = w >> 1, wn = w & 1;
    const int g    = lane >> 4, c = lane & 15;
    const int bm   = blockIdx.y * BM;
    const int bn   = blockIdx.x * BN;
    const int K    = 1024;

    f32x4 acc[4][4] = {};

    float4 fa[4];
    float4 fb[4];
    uint4  ha[2];

    auto load_tile = [&](int kt) {
        const int kb = kt * BKK;
        if (A_HALF) {
            const half_t* A = (const half_t*)Ap;
#pragma unroll
            for (int i = 0; i < 2; ++i) {
                const int row = (tid >> 2) + i * 64;
                const int col = (tid & 3) * 8;
                ha[i] = *(const uint4*)&A[(size_t)(bm + row) * K + kb + col];
            }
        } else {
            const float* A = (const float*)Ap;
#pragma unroll
            for (int i = 0; i < 4; ++i) {
                const int row = (tid >> 3) + i * 32;
                const int col = (tid & 7) * 4;
                fa[i] = *(const float4*)&A[(size_t)(bm + row) * K + kb + col];
            }
        }
#pragma unroll
        for (int i = 0; i < 4; ++i) {
            const int row = (tid >> 3) + i * 32;
            const int col = (tid & 7) * 4;
            fb[i] = *(const float4*)&Bp[(size_t)(bn + row) * K + kb + col];
        }
    };

    auto store_tile = [&]() {
        if (A_HALF) {
#pragma unroll
            for (int i = 0; i < 2; ++i) {
                const int row = (tid >> 2) + i * 64;
                const int col = (tid & 3) * 8;
                *(uint4*)&As[row * LDT + col] = ha[i];
            }
        } else {
#pragma unroll
            for (int i = 0; i < 4; ++i) {
                const int row = (tid >> 3) + i * 32;
                const int col = (tid & 7) * 4;
                half4 h = { (half_t)fa[i].x, (half_t)fa[i].y, (half_t)fa[i].z, (half_t)fa[i].w };
                *(half4*)&As[row * LDT + col] = h;
            }
        }
#pragma unroll
        for (int i = 0; i < 4; ++i) {
            const int row = (tid >> 3) + i * 32;
            const int col = (tid & 7) * 4;
            half4 h = { (half_t)fb[i].x, (half_t)fb[i].y, (half_t)fb[i].z, (half_t)fb[i].w };
            *(half4*)&Bs[row * LDT + col] = h;
        }
    };

    load_tile(0);
    const int NT = K / BKK;  // 32
    for (int kt = 0; kt < NT; ++kt) {
        __syncthreads();
        store_tile();
        __syncthreads();
        if (kt + 1 < NT) load_tile(kt + 1);

        half8 af[4], bf[4];
#pragma unroll
        for (int mt = 0; mt < 4; ++mt)
            af[mt] = *(const half8*)&As[(wm * 64 + mt * 16 + c) * LDT + g * 8];
#pragma unroll
        for (int nt = 0; nt < 4; ++nt)
            bf[nt] = *(const half8*)&Bs[(wn * 64 + nt * 16 + c) * LDT + g * 8];
#pragma unroll
        for (int mt = 0; mt < 4; ++mt)
#pragma unroll
            for (int nt = 0; nt < 4; ++nt)
                acc[mt][nt] = __builtin_amdgcn_mfma_f32_16x16x32_f16(af[mt], bf[nt], acc[mt][nt], 0, 0, 0);
    }

#pragma unroll
    for (int mt = 0; mt < 4; ++mt)
#pragma unroll
        for (int nt = 0; nt < 4; ++nt)
#pragma unroll
            for (int j = 0; j < 4; ++j) {
                const int gm = bm + wm * 64 + mt * 16 + g * 4 + j;
                const int gn = bn + wn * 64 + nt * 16 + c;
                const float val = acc[mt][nt][j] + bias[gn];
                if (OUTMODE == 0) {
                    const int b = gm >> 11, s = gm & 2047, h = gn >> 6, d = gn & 63;
                    ((half_t*)outp)[((size_t)(b * NHEAD + h) * SEQ + s) * HDIM + d] = (half_t)val;
                } else if (OUTMODE == 1) {
                    const int b = gm >> 11, s = gm & 2047, h = gn >> 6, d = gn & 63;
                    ((half_t*)outp)[((size_t)(b * NHEAD + h) * HDIM + d) * SEQ + s] = (half_t)val;
                } else {
                    ((float*)outp)[(size_t)gm * 1024 + gn] = val;
                }
            }
}

// ---------------------------------------------------------------------------
// Fused attention per (b,h, 16-row q-block):
//   scores in registers -> softmax (shfl + LDS) -> normalize in regs ->
//   nontemporal fire-and-forget attn store to d_out ->
//   PV via wave-local LDS transpose of P (no global round-trip).
// XCD-swizzled grid: each XCD owns 8 heads (K+V = 4 MB = its L2).
// ---------------------------------------------------------------------------
__global__ __launch_bounds__(256)
void attn_fused(const half_t* __restrict__ qh, const half_t* __restrict__ kh,
                const half_t* __restrict__ vT, float* __restrict__ attn,
                half_t* __restrict__ ctx)
{
    __shared__ float redmax[4][16];
    __shared__ float redsum[4][16];
    __shared__ float ctxred[4][16][64];
    __shared__ half_t pbuf[4][2][16][40];  // [wave][dbuf][qrow][k 0..31 + pad]

    const int bid0 = blockIdx.x;
    const int bid  = (bid0 & 7) * 1024 + (bid0 >> 3);  // XCD-contiguous heads
    const int bh   = bid >> 7;     // 0..63
    const int qb   = bid & 127;
    const int tid  = threadIdx.x;
    const int w    = tid >> 6;
    const int lane = tid & 63;
    const int g    = lane >> 4, c = lane & 15;
    const int qbase = qb * 16;
    const size_t hoff = (size_t)bh * SEQ * HDIM;

    // Q fragments (A operand): row = c, k = g*8 (+32 for second half of hd)
    const half8 a0 = *(const half8*)&qh[hoff + (size_t)(qbase + c) * HDIM + g * 8];
    const half8 a1 = *(const half8*)&qh[hoff + (size_t)(qbase + c) * HDIM + g * 8 + 32];

    const int cb = w * 512;  // this wave's k-column range
    f32x4 s[32];
#pragma unroll
    for (int t = 0; t < 32; ++t) {
        const int kc = cb + t * 16;
        const half8 b0 = *(const half8*)&kh[hoff + (size_t)(kc + c) * HDIM + g * 8];
        const half8 b1 = *(const half8*)&kh[hoff + (size_t)(kc + c) * HDIM + g * 8 + 32];
        f32x4 a = {0.f, 0.f, 0.f, 0.f};
        a = __builtin_amdgcn_mfma_f32_16x16x32_f16(a0, b0, a, 0, 0, 0);
        a = __builtin_amdgcn_mfma_f32_16x16x32_f16(a1, b1, a, 0, 0, 0);
        s[t] = a * 0.125f;   // 1/sqrt(64)
    }

    // --- row max (rows g*4+j live in lanes g*16..g*16+15, cols = c x tiles)
    float mrow[4] = {-1e30f, -1e30f, -1e30f, -1e30f};
#pragma unroll
    for (int t = 0; t < 32; ++t)
#pragma unroll
        for (int j = 0; j < 4; ++j) mrow[j] = fmaxf(mrow[j], s[t][j]);
#pragma unroll
    for (int j = 0; j < 4; ++j) {
        mrow[j] = fmaxf(mrow[j], __shfl_xor(mrow[j], 1));
        mrow[j] = fmaxf(mrow[j], __shfl_xor(mrow[j], 2));
        mrow[j] = fmaxf(mrow[j], __shfl_xor(mrow[j], 4));
        mrow[j] = fmaxf(mrow[j], __shfl_xor(mrow[j], 8));
    }
    if (c == 0) {
#pragma unroll
        for (int j = 0; j < 4; ++j) redmax[w][g * 4 + j] = mrow[j];
    }
    __syncthreads();
    float M[4];
#pragma unroll
    for (int j = 0; j < 4; ++j) {
        const int r = g * 4 + j;
        M[j] = fmaxf(fmaxf(redmax[0][r], redmax[1][r]), fmaxf(redmax[2][r], redmax[3][r]));
    }

    // --- exp + row sum
    float sum[4] = {0.f, 0.f, 0.f, 0.f};
#pragma unroll
    for (int t = 0; t < 32; ++t)
#pragma unroll
        for (int j = 0; j < 4; ++j) {
            const float p = __expf(s[t][j] - M[j]);
            s[t][j] = p;
            sum[j] += p;
        }
#pragma unroll
    for (int j = 0; j < 4; ++j) {
        sum[j] += __shfl_xor(sum[j], 1);
        sum[j] += __shfl_xor(sum[j], 2);
        sum[j] += __shfl_xor(sum[j], 4);
        sum[j] += __shfl_xor(sum[j], 8);
    }
    if (c == 0) {
#pragma unroll
        for (int j = 0; j < 4; ++j) redsum[w][g * 4 + j] = sum[j];
    }
    __syncthreads();
    float inv[4];
#pragma unroll
    for (int j = 0; j < 4; ++j) {
        const int r = g * 4 + j;
        inv[j] = 1.0f / (redsum[0][r] + redsum[1][r] + redsum[2][r] + redsum[3][r]);
    }

    // --- normalize in regs, fire-and-forget nontemporal attn store
    float* arow = attn + (size_t)(bh * SEQ + qbase) * SEQ;
#pragma unroll
    for (int t = 0; t < 32; ++t)
#pragma unroll
        for (int j = 0; j < 4; ++j) {
            s[t][j] *= inv[j];
            __builtin_nontemporal_store(s[t][j],
                &arow[(size_t)(g * 4 + j) * SEQ + cb + t * 16 + c]);
        }

    // --- PV: wave-local LDS transpose of P into A-fragment layout, V from L2
    const half_t* vbase = vT + (size_t)bh * HDIM * SEQ;
    f32x4 cacc[4] = {};
#pragma unroll
    for (int kt = 0; kt < 16; ++kt) {
        const int kb = kt & 1;
#pragma unroll
        for (int j = 0; j < 4; ++j) {
            pbuf[w][kb][g * 4 + j][c]      = (half_t)s[2 * kt][j];
            pbuf[w][kb][g * 4 + j][16 + c] = (half_t)s[2 * kt + 1][j];
        }
        asm volatile("s_waitcnt lgkmcnt(0)" ::: "memory");
        const half8 pa = *(const half8*)&pbuf[w][kb][c][g * 8];
        const int k0 = cb + kt * 32 + g * 8;
#pragma unroll
        for (int nt = 0; nt < 4; ++nt) {
            const half8 vb = *(const half8*)&vbase[(size_t)(nt * 16 + c) * SEQ + k0];
            cacc[nt] = __builtin_amdgcn_mfma_f32_16x16x32_f16(pa, vb, cacc[nt], 0, 0, 0);
        }
    }
#pragma unroll
    for (int nt = 0; nt < 4; ++nt)
#pragma unroll
        for (int j = 0; j < 4; ++j)
            ctxred[w][g * 4 + j][nt * 16 + c] = cacc[nt][j];
    __syncthreads();

    const int b = bh >> 4, h = bh & 15;
#pragma unroll
    for (int i = 0; i < 4; ++i) {
        const int p   = tid + 256 * i;
        const int row = p >> 6, col = p & 63;
        const float v = ctxred[0][row][col] + ctxred[1][row][col] +
                        ctxred[2][row][col] + ctxred[3][row][col];
        ctx[(size_t)(b * SEQ + qbase + row) * D_MODEL + h * HDIM + col] = (half_t)v;
    }
}

// ---------------------------------------------------------------------------
extern "C" void kernel_launch(void* const* d_in, const int* in_sizes, int n_in,
                              void* d_out, int out_size, void* d_ws, size_t ws_size,
                              hipStream_t stream) {
    const float* Qin = (const float*)d_in[0];
    const float* Kin = (const float*)d_in[1];
    const float* Vin = (const float*)d_in[2];
    const float* WQw = (const float*)d_in[3];
    const float* WQb = (const float*)d_in[4];
    const float* WKw = (const float*)d_in[5];
    const float* WKb = (const float*)d_in[6];
    const float* WVw = (const float*)d_in[7];
    const float* WVb = (const float*)d_in[8];
    const float* WOw = (const float*)d_in[9];
    const float* WOb = (const float*)d_in[10];

    char* ws = (char*)d_ws;
    half_t* qh  = (half_t*)(ws);
    half_t* kh  = (half_t*)(ws + (size_t)16 * 1024 * 1024);
    half_t* vT  = (half_t*)(ws + (size_t)32 * 1024 * 1024);
    half_t* ctx = (half_t*)(ws + (size_t)48 * 1024 * 1024);

    float* out  = (float*)d_out;
    float* attn = out + (size_t)M_TOTAL * D_MODEL;   // 8,388,608

    dim3 grid(8, 64), blk(256);
    hipLaunchKernelGGL((gemm_bt<0, false>), grid, blk, 0, stream, Qin, WQw, WQb, qh);
    hipLaunchKernelGGL((gemm_bt<0, false>), grid, blk, 0, stream, Kin, WKw, WKb, kh);
    hipLaunchKernelGGL((gemm_bt<1, false>), grid, blk, 0, stream, Vin, WVw, WVb, vT);
    hipLaunchKernelGGL(attn_fused, dim3(64 * 128), blk, 0, stream, qh, kh, vT, attn, ctx);
    hipLaunchKernelGGL((gemm_bt<2, true>), grid, blk, 0, stream, ctx, WOw, WOb, out);
}